// Round 3
// baseline (341.904 us; speedup 1.0000x reference)
//
#include <hip/hip_runtime.h>
#include <hip/hip_bf16.h>
#include <hip/hip_fp16.h>
#include <type_traits>

#define DM 1024
#define NH 16
#define HD 64
#define BATCH 2
#define SEQ 2048
#define MROWS (BATCH*SEQ)   // 4096

typedef __hip_bfloat16 bf16;
typedef __attribute__((ext_vector_type(8))) short    bf16x8;
typedef __attribute__((ext_vector_type(8))) _Float16 f16x8;
typedef __attribute__((ext_vector_type(4))) _Float16 f16x4;
typedef __attribute__((ext_vector_type(4))) float    f32x4;

#define NEG_BIG (-30000.0f)   // dominates any real score but exp2f-safe

__device__ __forceinline__ short f2bf(float x) {   // RNE f32->bf16, finite inputs
    union { float f; unsigned u; } v; v.f = x;
    unsigned r = v.u + 0x7FFF + ((v.u >> 16) & 1);
    return (short)(r >> 16);
}

__device__ __forceinline__ bf16x8 ld8f(const float* p) {  // 8 f32 -> bf16x8
    const float4 a = *(const float4*)p;
    const float4 b = *(const float4*)(p + 4);
    bf16x8 r;
    r[0]=f2bf(a.x); r[1]=f2bf(a.y); r[2]=f2bf(a.z); r[3]=f2bf(a.w);
    r[4]=f2bf(b.x); r[5]=f2bf(b.y); r[6]=f2bf(b.z); r[7]=f2bf(b.w);
    return r;
}

// C[M,N] = A[M,K] @ W[N,K]^T + bias.  M=4096, N=K=1024.  W,bias: float32.
// TA: float (seq) or bf16-as-short (attn output buffer).
// MODE 0: store float32 row-major [M,N] to d_out (z must be 0)
// MODE 1: store f16 permuted to [B,H,T,Dh]  (z in {0,1,2} selects W/bias/out)
template<typename TA, int MODE>
__global__ __launch_bounds__(256)
void gemm_bt(const TA* __restrict__ A,
             const float* __restrict__ W0, const float* __restrict__ W1, const float* __restrict__ W2,
             const float* __restrict__ b0, const float* __restrict__ b1, const float* __restrict__ b2,
             void* o0, void* o1, void* o2)
{
    __shared__ __align__(16) short lA[128*32];   // 8 KB, row-major [128][32]
    __shared__ __align__(16) short lB[128*32];

    const int tid  = threadIdx.x;
    const int wid  = tid >> 6;
    const int lane = tid & 63;
    const int tile_n = blockIdx.x * 128;
    const int tile_m = blockIdx.y * 128;
    const int z = blockIdx.z;

    const float* Wg = (z == 0 ? W0 : (z == 1 ? W1 : W2));
    const float* bi = (z == 0 ? b0 : (z == 1 ? b1 : b2));
    void*        out = (z == 0 ? o0 : (z == 1 ? o1 : o2));

    // staging: wave w covers rows w*32 .. w*32+31 of the 128x32 tile
    const int sa_row = tile_m + wid*32 + (lane >> 2);
    const int sb_row = tile_n + wid*32 + (lane >> 2);
    const int scol   = (lane & 3) * 8;                 // k-offset in elements
    short* lA0 = lA + wid*1024 + lane*8;               // row-major [128][32]
    short* lA1 = lA0 + 512;
    short* lB0 = lB + wid*1024 + lane*8;
    short* lB1 = lB0 + 512;

    const int wm = (wid >> 1) * 64;
    const int wn = (wid & 1) * 64;
    const int fr = lane & 15;
    const int quad = lane >> 4;
    const int fq = quad * 8;

    f32x4 acc[4][4] = {};

    for (int k0 = 0; k0 < DM; k0 += 32) {
        bf16x8 ra0, ra1;
        if constexpr (std::is_same<TA, float>::value) {
            ra0 = ld8f((const float*)A + (size_t)sa_row*DM      + k0 + scol);
            ra1 = ld8f((const float*)A + (size_t)(sa_row+16)*DM + k0 + scol);
        } else {
            ra0 = *(const bf16x8*)((const short*)A + (size_t)sa_row*DM      + k0 + scol);
            ra1 = *(const bf16x8*)((const short*)A + (size_t)(sa_row+16)*DM + k0 + scol);
        }
        const bf16x8 rb0 = ld8f(Wg + (size_t)sb_row*DM      + k0 + scol);
        const bf16x8 rb1 = ld8f(Wg + (size_t)(sb_row+16)*DM + k0 + scol);

        __syncthreads();               // previous iteration's LDS reads complete
        *(bf16x8*)lA0 = ra0;
        *(bf16x8*)lA1 = ra1;
        *(bf16x8*)lB0 = rb0;
        *(bf16x8*)lB1 = rb1;
        __syncthreads();               // LDS writes visible

        bf16x8 af[4], bfv[4];
        #pragma unroll
        for (int i = 0; i < 4; ++i) af[i]  = *(const bf16x8*)(lA + (wm + i*16 + fr)*32 + fq);
        #pragma unroll
        for (int i = 0; i < 4; ++i) bfv[i] = *(const bf16x8*)(lB + (wn + i*16 + fr)*32 + fq);

        #pragma unroll
        for (int mi = 0; mi < 4; ++mi)
            #pragma unroll
            for (int ni = 0; ni < 4; ++ni)
                acc[mi][ni] = __builtin_amdgcn_mfma_f32_16x16x32_bf16(
                    af[mi], bfv[ni], acc[mi][ni], 0, 0, 0);
    }

    // epilogue: C/D layout col=lane&15, row=quad*4+reg
    #pragma unroll
    for (int mi = 0; mi < 4; ++mi) {
        #pragma unroll
        for (int ni = 0; ni < 4; ++ni) {
            const int colg = tile_n + wn + ni*16 + fr;
            const float bia = bi[colg];
            #pragma unroll
            for (int r = 0; r < 4; ++r) {
                const int rowg = tile_m + wm + mi*16 + quad*4 + r;
                const float v = acc[mi][ni][r] + bia;
                if (MODE == 0) {
                    ((float*)out)[(size_t)rowg*DM + colg] = v;
                } else {
                    const int bb = rowg >> 11, t = rowg & (SEQ-1);
                    const int h  = colg >> 6,  d = colg & (HD-1);
                    ((_Float16*)out)[(((size_t)(bb*NH + h))*SEQ + t)*HD + d] = (_Float16)v;
                }
            }
        }
    }
}

// Flash attention, causal. Q,K,V: [B,H,T,64] f16. O: [B,T,1024] bf16 (as short).
// One wave per 16-row Q tile; S^T = K*Q^T trick: S^T C-frag (row=key=quad*4+r,
// col=q=lane&15) is directly the A-operand layout of the PV mfma_16x16x16f16.
__global__ __launch_bounds__(256)
void attn(const _Float16* __restrict__ Q, const _Float16* __restrict__ K,
          const _Float16* __restrict__ V, short* __restrict__ O)
{
    const int lane = threadIdx.x & 63;
    const int wid  = threadIdx.x >> 6;
    const int bh   = blockIdx.y;
    const int q_base = blockIdx.x*64 + wid*16;
    const size_t base = (size_t)bh * SEQ * HD;
    const int qr = lane & 15;
    const int quad = lane >> 4;

    // Q fragments (B-operand of S^T mfma): B[k][n=lane&15=q] = Q[q][k], k = quad*8+j
    const f16x8* Qv = (const f16x8*)(Q + base + (size_t)(q_base + qr)*HD);
    const f16x8 qf0 = Qv[quad];
    const f16x8 qf1 = Qv[quad + 4];

    float m_cur = NEG_BIG, l_cur = 0.f;
    f32x4 o[4] = {};
    const int q_idx = q_base + qr;
    const int nkt = (q_base >> 4) + 1;   // causal: only tiles with k_base <= q_base+15

    for (int kt = 0; kt < nkt; ++kt) {
        const int k_base = kt * 16;
        // K fragments (A-operand): A[m=lane&15=key][k=quad*8+j]
        const f16x8* Kv = (const f16x8*)(K + base + (size_t)(k_base + qr)*HD);
        const f16x8 kf0 = Kv[quad];
        const f16x8 kf1 = Kv[quad + 4];

        f32x4 s = {};
        s = __builtin_amdgcn_mfma_f32_16x16x32_f16(kf0, qf0, s, 0, 0, 0);
        s = __builtin_amdgcn_mfma_f32_16x16x32_f16(kf1, qf1, s, 0, 0, 0);
        // s[r] = S^T[key = k_base+quad*4+r][q = lane&15]

        float sv[4];
        float mloc = NEG_BIG;
        #pragma unroll
        for (int r = 0; r < 4; ++r) {
            const int key = k_base + quad*4 + r;
            const float x = s[r] * 0.125f;           // 1/sqrt(64)
            sv[r] = (key <= q_idx) ? x : NEG_BIG;
            mloc = fmaxf(mloc, sv[r]);
        }
        // per-q reduction across the 4 quads (bits 4,5 of lane id)
        mloc = fmaxf(mloc, __shfl_xor(mloc, 16, 64));
        mloc = fmaxf(mloc, __shfl_xor(mloc, 32, 64));
        const float m_new = fmaxf(m_cur, mloc);
        const float alpha = exp2f((m_cur - m_new) * 1.44269504f);

        f16x4 pf;
        float psum = 0.f;
        #pragma unroll
        for (int r = 0; r < 4; ++r) {
            const float p = exp2f((sv[r] - m_new) * 1.44269504f);
            psum += p;
            pf[r] = (_Float16)p;
        }
        psum += __shfl_xor(psum, 16, 64);
        psum += __shfl_xor(psum, 32, 64);
        l_cur = l_cur * alpha + psum;
        m_cur = m_new;

        // O-frag rows are q = quad*4+r; alpha for q lives at lane q (lanes 0..15)
        float ar[4];
        #pragma unroll
        for (int r = 0; r < 4; ++r) ar[r] = __shfl(alpha, quad*4 + r, 64);

        #pragma unroll
        for (int dt = 0; dt < 4; ++dt) {
            #pragma unroll
            for (int r = 0; r < 4; ++r) o[dt][r] *= ar[r];
            // V fragment (B-operand, K=16): B[k=quad*4+j][n=lane&15=d]
            f16x4 vf;
            #pragma unroll
            for (int j = 0; j < 4; ++j)
                vf[j] = V[base + (size_t)(k_base + quad*4 + j)*HD + dt*16 + qr];
            o[dt] = __builtin_amdgcn_mfma_f32_16x16x16f16(pf, vf, o[dt], 0, 0, 0);
        }
    }

    float lr[4];
    #pragma unroll
    for (int r = 0; r < 4; ++r) lr[r] = fmaxf(__shfl(l_cur, quad*4 + r, 64), 1e-30f);

    const int bb = bh >> 4, h = bh & (NH-1);
    #pragma unroll
    for (int dt = 0; dt < 4; ++dt) {
        #pragma unroll
        for (int r = 0; r < 4; ++r) {
            const int t = q_base + quad*4 + r;
            O[((size_t)(bb*SEQ + t))*DM + h*HD + dt*16 + qr] =
                f2bf(o[dt][r] / lr[r]);
        }
    }
}

extern "C" void kernel_launch(void* const* d_in, const int* in_sizes, int n_in,
                              void* d_out, int out_size, void* d_ws, size_t ws_size,
                              hipStream_t stream)
{
    const float* seq = (const float*)d_in[0];
    const float* wq  = (const float*)d_in[1];
    const float* bq  = (const float*)d_in[2];
    const float* wk  = (const float*)d_in[3];
    const float* bk  = (const float*)d_in[4];
    const float* wv  = (const float*)d_in[5];
    const float* bv  = (const float*)d_in[6];
    const float* wo  = (const float*)d_in[7];
    const float* bo  = (const float*)d_in[8];

    _Float16* Qb = (_Float16*)d_ws;                    //  8 MB
    _Float16* Kb = Qb + (size_t)MROWS*DM;              //  8 MB
    _Float16* Vb = Kb + (size_t)MROWS*DM;              //  8 MB
    short*    Ob = (short*)(Vb + (size_t)MROWS*DM);    //  8 MB bf16 (32 MB total)

    dim3 g1(DM/128, MROWS/128, 3);
    gemm_bt<float, 1><<<g1, 256, 0, stream>>>(seq, wq, wk, wv, bq, bk, bv,
                                              (void*)Qb, (void*)Kb, (void*)Vb);

    dim3 g2(SEQ/64, BATCH*NH, 1);
    attn<<<g2, 256, 0, stream>>>(Qb, Kb, Vb, Ob);

    dim3 g3(DM/128, MROWS/128, 1);
    gemm_bt<short, 0><<<g3, 256, 0, stream>>>(Ob, wo, wo, wo, bo, bo, bo,
                                              d_out, d_out, d_out);
}